// Round 4
// baseline (242.489 us; speedup 1.0000x reference)
//
#include <hip/hip_runtime.h>
#include <math.h>

// DegreeQuantileConverter — MEASUREMENT ROUND (R5).
//
// Evidence: R1 118.9 / R2 117.5 / R4 117.3 us — three structurally different
// kernels (heavy-VALU one-shot; slim-VALU grid-stride nt; 4x-ILP pipelined)
// are identical within noise. VALU count, grid shape, store cache-mode, and
// load-latency ILP are ALL eliminated as limiters. Meanwhile rocprof top-5
// shows only harness re-poison fills (402 MB @6.2 TB/s, ~65 us) and our
// kernel never appears => kernel dur < 64 us, so dur_us = fixed_overhead + K
// with K in [17, 64] us. Can't tell Case A (K~17, already roofline, overhead
// ~100us) from Case B (K~50, real scale-invariant limiter) without the
// kernel's OWN counter row.
//
// This round: reps=8 loop with memory-clobber barriers (idempotent stores,
// still numerically correct) to make the kernel ~8x longer so it lands in
// top-5 with its own dur/WRITE_SIZE/VGPR/Occupancy/VALUBusy.
//   Case A prediction: dqc row dur 125-140us, ~6 TB/s; total ~215-240.
//   Case B prediction: dqc row dur 380-430us, ~2 TB/s; counters name limiter.
// Next round reverts reps to 1 regardless.

#define LOG_EPS_F (-69.07755278982137f)  // logf(1e-30f)

typedef float f32x4 __attribute__((ext_vector_type(4)));

__device__ __forceinline__ f32x4 dqc_item(float deg, unsigned part)
{
    // searchsorted(q, deg, 'right') - 1 via exponent bits (q = [0,1,2,4,...,1024]):
    // deg in [2^(i-1), 2^i) -> idx = i ; deg in [0,1) -> idx = 0.
    unsigned bits = __float_as_uint(deg);
    int idx = (int)(bits >> 23) - 126;            // exponent + 1
    idx = idx < 0 ? 0 : (idx > 10 ? 10 : idx);    // clamp to [0, 10]

    // lo = q[idx] = (idx ? 2^(idx-1) : 0); 1/(hi-lo) = (idx ? 2^(1-idx) : 1)
    float lo  = (idx == 0) ? 0.0f
                           : __uint_as_float((unsigned)(idx + 126) << 23);
    float inv = (idx == 0) ? 1.0f
                           : __uint_as_float((unsigned)(128 - idx) << 23);

    float pos = (deg - lo) * inv;
    pos = fminf(fmaxf(pos, 0.0f), 1.0f);          // v_med3

    bool top      = (deg >= 1024.0f);             // whole row -> 0.0f
    bool in_range = (deg >= 0.0f) && !top;

    float w_lo = in_range ? (1.0f - pos) : 0.0f;
    float w_hi = in_range ? pos          : 0.0f;
    float lw_lo = __logf(w_lo + 1e-30f);          // v_log_f32 * ln2
    float lw_hi = __logf(w_hi + 1e-30f);
    float fill  = LOG_EPS_F;
    if (top) { lw_lo = 0.0f; lw_hi = 0.0f; fill = 0.0f; }

    int j0 = (int)part * 4;
    f32x4 o;
#pragma unroll
    for (int u = 0; u < 4; ++u) {
        int j = j0 + u;
        float x = fill;
        x = (j == idx)     ? lw_lo : x;
        x = (j == idx + 1) ? lw_hi : x;
        o[u] = x;
    }
    return o;
}

__global__ __launch_bounds__(256) void dqc_kernel(
    const float* __restrict__ deg_in,
    const float* __restrict__ q,       // unused: structure hard-coded
    f32x4* __restrict__ out,
    unsigned nvec,
    unsigned reps)
{
    (void)q;
    const unsigned stride = gridDim.x * 256u;
    const unsigned t0 = blockIdx.x * 256u + threadIdx.x;

    for (unsigned rep = 0; rep < reps; ++rep) {
        if (nvec == 12u * stride) {
            // Exact-shape fast path (nvec = 6,291,456 = 12 * 2048 * 256):
            // 4 loads issued up front, then 4 compute+store (R4 structure).
            unsigned t = t0;
#pragma unroll 1
            for (int outer = 0; outer < 3; ++outer) {
                float    d[4];
                unsigned pp[4];
#pragma unroll
                for (int k = 0; k < 4; ++k) {
                    unsigned tt = t + (unsigned)k * stride;
                    unsigned r  = tt / 3u;           // magic-mul div by 3
                    d[k]  = deg_in[r];
                    pp[k] = tt - r * 3u;
                }
#pragma unroll
                for (int k = 0; k < 4; ++k) {
                    f32x4 o = dqc_item(d[k], pp[k]);
                    __builtin_nontemporal_store(o, &out[t + (unsigned)k * stride]);
                }
                t += 4u * stride;
            }
        } else {
            for (unsigned t = t0; t < nvec; t += stride) {
                unsigned r = t / 3u;
                f32x4 o = dqc_item(deg_in[r], t - r * 3u);
                __builtin_nontemporal_store(o, &out[t]);
            }
        }
        // Opaque memory barrier: keeps the per-rep stores alive (measurement
        // knob only; stores are idempotent so output is unchanged).
        __asm__ volatile("" ::: "memory");
    }
}

extern "C" void kernel_launch(void* const* d_in, const int* in_sizes, int n_in,
                              void* d_out, int out_size, void* d_ws, size_t ws_size,
                              hipStream_t stream) {
    const float* deg = (const float*)d_in[0];  // (B*S,) flat, 2,097,152
    const float* q   = (const float*)d_in[1];  // (12,)
    f32x4* out       = (f32x4*)d_out;          // (B*S*12,) f32, 12%4==0

    unsigned nvec   = (unsigned)(out_size / 4);     // 6,291,456 float4s
    unsigned want   = (nvec + 255u) / 256u;
    unsigned blocks = want < 2048u ? want : 2048u;  // grid-stride the rest

    dqc_kernel<<<blocks, 256, 0, stream>>>(deg, q, out, nvec, 8u /* MEASUREMENT */);
}

// Round 5
// 116.504 us; speedup vs baseline: 2.0814x; 2.0814x over previous
//
#include <hip/hip_runtime.h>
#include <math.h>

// DegreeQuantileConverter:
//   deg: (B,S,1) f32, q: (12,) f32 = [0,1,2,4,...,1024]  (fixed by problem spec)
//   out: (B,S,12) f32 = log(w + 1e-30), w = linear-interp 2-hot row
//   (idx = searchsorted_right(q,deg)-1 clipped to [0,10]); whole row = 0.0f
//   when deg >= 1024.
//
// ROOFLINE ESTABLISHED (R5 measurement round, reps=8 probe):
//   marginal cost/rep = (242.49-117.26)/7 = 17.89 us for ~98 MB write
//     -> 6.1 TB/s, 97% of the harness fill's own 6.2 TB/s on this buffer,
//     within 3% of the 17.3 us ideal floor (109 MB @ 6.3 TB/s).
//   K1=17.9 predicts dur(reps=8) = 99.4 + 8*17.9 = 242.6 vs measured 242.49.
//   => kernel ~= 17.9 us AT the write-streaming roofline; graded dur_us is
//   ~99 us fixed harness overhead (65 us re-poison fill + restores) + kernel.
//   This explains R1/R2/R4 (118.9 / 117.5 / 117.3) being indistinguishable.
// Counter row: 32 VGPR, 57% occupancy, 0 LDS conflicts, FETCH 5.3 MB (no
// over-fetch), WRITE = exactly 8x output.
//
// This file: R4 kernel verbatim (harness-verified 117.26 us, absmax 0.0156),
// measurement reps loop removed.

#define LOG_EPS_F (-69.07755278982137f)  // logf(1e-30f)

typedef float f32x4 __attribute__((ext_vector_type(4)));

__device__ __forceinline__ f32x4 dqc_item(float deg, unsigned part)
{
    // searchsorted(q, deg, 'right') - 1 via exponent bits (q = [0,1,2,4,...,1024]):
    // deg in [2^(i-1), 2^i) -> idx = i ; deg in [0,1) -> idx = 0.
    unsigned bits = __float_as_uint(deg);
    int idx = (int)(bits >> 23) - 126;            // exponent + 1
    idx = idx < 0 ? 0 : (idx > 10 ? 10 : idx);    // clamp to [0, 10]
    // (negative deg gives a garbage idx, but then in_range=false -> weights 0
    //  -> whole row LOG_EPS regardless of idx, matching the reference)

    // lo = q[idx] = (idx ? 2^(idx-1) : 0); 1/(hi-lo) = (idx ? 2^(1-idx) : 1)
    float lo  = (idx == 0) ? 0.0f
                           : __uint_as_float((unsigned)(idx + 126) << 23);
    float inv = (idx == 0) ? 1.0f
                           : __uint_as_float((unsigned)(128 - idx) << 23);

    float pos = (deg - lo) * inv;
    pos = fminf(fmaxf(pos, 0.0f), 1.0f);          // v_med3

    bool top      = (deg >= 1024.0f);             // whole row -> 0.0f
    bool in_range = (deg >= 0.0f) && !top;

    float w_lo = in_range ? (1.0f - pos) : 0.0f;
    float w_hi = in_range ? pos          : 0.0f;
    float lw_lo = __logf(w_lo + 1e-30f);          // v_log_f32 * ln2
    float lw_hi = __logf(w_hi + 1e-30f);
    float fill  = LOG_EPS_F;
    if (top) { lw_lo = 0.0f; lw_hi = 0.0f; fill = 0.0f; }

    int j0 = (int)part * 4;
    f32x4 o;
#pragma unroll
    for (int u = 0; u < 4; ++u) {
        int j = j0 + u;
        float x = fill;
        x = (j == idx)     ? lw_lo : x;
        x = (j == idx + 1) ? lw_hi : x;
        o[u] = x;
    }
    return o;
}

__global__ __launch_bounds__(256) void dqc_kernel(
    const float* __restrict__ deg_in,
    const float* __restrict__ q,       // unused: structure hard-coded (see hdr)
    f32x4* __restrict__ out,
    unsigned nvec)
{
    (void)q;
    const unsigned stride = gridDim.x * 256u;
    const unsigned t0 = blockIdx.x * 256u + threadIdx.x;

    if (nvec == 12u * stride) {
        // Exact-shape fast path (nvec = 6,291,456 = 12 * 2048 * 256):
        // 4 loads issued up front, then 4 compute+store. No bounds checks.
        unsigned t = t0;
#pragma unroll 1
        for (int outer = 0; outer < 3; ++outer) {
            float    d[4];
            unsigned pp[4];
#pragma unroll
            for (int k = 0; k < 4; ++k) {
                unsigned tt = t + (unsigned)k * stride;
                unsigned r  = tt / 3u;           // magic-mul div by 3
                d[k]  = deg_in[r];
                pp[k] = tt - r * 3u;
            }
#pragma unroll
            for (int k = 0; k < 4; ++k) {
                f32x4 o = dqc_item(d[k], pp[k]);
                __builtin_nontemporal_store(o, &out[t + (unsigned)k * stride]);
            }
            t += 4u * stride;
        }
    } else {
        // Generic fallback
        for (unsigned t = t0; t < nvec; t += stride) {
            unsigned r = t / 3u;
            f32x4 o = dqc_item(deg_in[r], t - r * 3u);
            __builtin_nontemporal_store(o, &out[t]);
        }
    }
}

extern "C" void kernel_launch(void* const* d_in, const int* in_sizes, int n_in,
                              void* d_out, int out_size, void* d_ws, size_t ws_size,
                              hipStream_t stream) {
    const float* deg = (const float*)d_in[0];  // (B*S,) flat, 2,097,152
    const float* q   = (const float*)d_in[1];  // (12,)
    f32x4* out       = (f32x4*)d_out;          // (B*S*12,) f32, 12%4==0

    unsigned nvec   = (unsigned)(out_size / 4);     // 6,291,456 float4s
    unsigned want   = (nvec + 255u) / 256u;
    unsigned blocks = want < 2048u ? want : 2048u;  // grid-stride the rest

    dqc_kernel<<<blocks, 256, 0, stream>>>(deg, q, out, nvec);
}